// Round 10
// baseline (212.124 us; speedup 1.0000x reference)
//
#include <hip/hip_runtime.h>
#include <stdint.h>
#include <stddef.h>

typedef __bf16 bf16;
typedef __bf16 bf16x8 __attribute__((ext_vector_type(8)));
typedef __bf16 bf16x4 __attribute__((ext_vector_type(4)));
typedef short short4v __attribute__((ext_vector_type(4)));
typedef float f32x4 __attribute__((ext_vector_type(4)));

#define GAS __attribute__((address_space(1)))
#define LAS __attribute__((address_space(3)))

__device__ __forceinline__ void async_load16(const void* g, void* l) {
  __builtin_amdgcn_global_load_lds((const GAS void*)g, (LAS void*)l, 16, 0, 0);
}

// 16x16x16 bf16 MFMA. C-layout of a 16x16 MFMA == B-layout of this shape,
// so P^T feeds PV straight from registers. Host pass gets a stub.
__device__ __forceinline__ f32x4 mfma16(bf16x4 a, bf16x4 b, f32x4 c) {
#if defined(__HIP_DEVICE_COMPILE__)
#if __has_builtin(__builtin_amdgcn_mfma_f32_16x16x16bf16_1k)
  return __builtin_amdgcn_mfma_f32_16x16x16bf16_1k(
      __builtin_bit_cast(short4v, a), __builtin_bit_cast(short4v, b), c, 0, 0, 0);
#else
  f32x4 d;
  asm volatile("v_mfma_f32_16x16x16_bf16 %0, %1, %2, %3"
               : "=v"(d)
               : "v"(a), "v"(b), "v"(c));
  return d;
#endif
#else
  (void)a; (void)b;
  return c;
#endif
}

// ---------------------------------------------------------------------------
// Kernel 1: fp32 -> bf16 casts, x4 vectorized. Wq pre-scaled by 0.125*log2(e)
// so QK^T lands in the exp2 domain. Blocks >= 8192 build the RoPE cos/sin
// table rope[s][ip] (float2, 2048x32 = 512KB).
// ---------------------------------------------------------------------------
__global__ __launch_bounds__(256) void cast_all(
    const float* __restrict__ x, const float* __restrict__ Wq,
    const float* __restrict__ Wk, const float* __restrict__ Wv,
    const float* __restrict__ Wo, bf16* __restrict__ Xh,
    bf16* __restrict__ Wqkv, bf16* __restrict__ Woh,
    float2* __restrict__ rope) {
  if (blockIdx.x >= 8192) {
    const int e = ((blockIdx.x - 8192) * 256 + threadIdx.x) * 4;
    const int s = e >> 5, ip0 = e & 31;
#pragma unroll
    for (int r = 0; r < 4; ++r) {
      const float freq = __expf((float)(ip0 + r) * -0.2878231366242557f);
      float sn, cs;
      __sincosf((float)s * freq, &sn, &cs);
      rope[e + r] = make_float2(cs, sn);
    }
    return;
  }
  int idx = (blockIdx.x * 256 + threadIdx.x) * 4;
  const float* src;
  bf16* dst;
  float scale = 1.0f;
  if (idx < 4194304) {
    src = x + idx; dst = Xh + idx;
  } else if (idx < 7340032) {
    int j = idx - 4194304;
    if (j < 1048576) {
      src = Wq + j; scale = 0.18033688011112042f;
    } else {
      src = ((j < 2097152) ? Wk : Wv) + (j & 1048575);
    }
    dst = Wqkv + j;
  } else {
    int j = idx - 7340032;
    src = Wo + j; dst = Woh + j;
  }
  float4 v = *(const float4*)src;
  bf16x4 o;
  o[0] = (bf16)(v.x * scale); o[1] = (bf16)(v.y * scale);
  o[2] = (bf16)(v.z * scale); o[3] = (bf16)(v.w * scale);
  *(bf16x4*)dst = o;
}

// ---------------------------------------------------------------------------
// Kernel 2: QKV projection with FUSED RoPE + V-transpose epilogue.
// BK=64 + both-sides XOR swizzle in the main loop (r18, verified).
// Q -> Qh linear; K -> Kh linear; V -> Vt col-swizzled (attn LDS path).
// ---------------------------------------------------------------------------
__global__ __launch_bounds__(256, 3) void gemm_qkv(
    const bf16* __restrict__ A, const bf16* __restrict__ B,
    const float2* __restrict__ rope, bf16* __restrict__ Qh,
    bf16* __restrict__ Kh, bf16* __restrict__ Vt, int K) {
  __shared__ __align__(16) bf16 As[128 * 64];
  __shared__ __align__(16) bf16 Bs[128 * 64];
  const int tid = threadIdx.x;
  const int wave = tid >> 6, lane = tid & 63;
  const int bm = blockIdx.y * 128, bn = blockIdx.x * 128;
  const int wm = (wave >> 1) * 64, wn = (wave & 1) * 64;
  const int fr = lane & 15, g = lane >> 4;
  const int sw8 = (fr & 7) * 8;  // read-side swizzle

  const int srow = tid >> 3;
  const int scol = 8 * ((tid & 7) ^ (srow & 7));
  const int ldst = wave * 512;

  f32x4 acc[4][4] = {};

  for (int kt = 0; kt < K; kt += 64) {
    __syncthreads();
#pragma unroll
    for (int s = 0; s < 4; ++s) {
      const int row = s * 32 + srow;
      async_load16(A + (size_t)(bm + row) * K + kt + scol,
                   (void*)(As + s * 2048 + ldst));
      async_load16(B + (size_t)(bn + row) * K + kt + scol,
                   (void*)(Bs + s * 2048 + ldst));
    }
    __syncthreads();

#pragma unroll
    for (int ks = 0; ks < 2; ++ks) {
      bf16x8 af[4], bfr[4];
      const int kq = (ks * 32 + g * 8) ^ sw8;
#pragma unroll
      for (int i = 0; i < 4; ++i)
        af[i] = *(const bf16x8*)&As[(wm + i * 16 + fr) * 64 + kq];
#pragma unroll
      for (int j = 0; j < 4; ++j)
        bfr[j] = *(const bf16x8*)&Bs[(wn + j * 16 + fr) * 64 + kq];
#pragma unroll
      for (int i = 0; i < 4; ++i)
#pragma unroll
        for (int j = 0; j < 4; ++j)
          acc[i][j] = __builtin_amdgcn_mfma_f32_16x16x32_bf16(af[i], bfr[j],
                                                              acc[i][j], 0, 0, 0);
    }
  }

  const int r0 = (lane >> 4) * 4, cc = lane & 15;
  const bool oddl = cc & 1;
#pragma unroll
  for (int i = 0; i < 4; ++i) {
    const int row0 = bm + wm + i * 16 + r0;
    const int b = row0 >> 11, s0 = row0 & 2047;
#pragma unroll
    for (int j = 0; j < 4; ++j) {
      const int col = bn + wn + j * 16 + cc;  // whole wave same region per j
      if (col < 2048) {
        // RoPE: pair partner is lane^1 (col 2k <-> 2k+1)
        const int hcol = col & 1023;
        const int h = hcol >> 6, d = hcol & 63;
        const int ip = d >> 1;
        const bool isK = col >= 1024;
        bf16* dst = (isK ? Kh : Qh) + ((size_t)(b * 16 + h) * 2048) * 64;
#pragma unroll
        for (int r = 0; r < 4; ++r) {
          float own = acc[i][j][r];
          float oth = __shfl_xor(own, 1, 64);
          const float2 t = rope[((s0 + r) << 5) + ip];
          float res = oddl ? (oth * t.y + own * t.x) : (own * t.x - oth * t.y);
          dst[(size_t)(s0 + r) * 64 + d] = (bf16)res;
        }
      } else {
        const int v = col - 2048, h = v >> 6, d = v & 63;
        bf16x4 o;
#pragma unroll
        for (int r = 0; r < 4; ++r) o[r] = (bf16)acc[i][j][r];
        // col-swizzled within each 64-wide tile (verified r18/r19); 4-run
        // at s0 stays contiguous (XOR touches bits 3..5, s0 is 4-aligned)
        const int s2 = (s0 & ~63) | ((s0 ^ ((d & 7) << 3)) & 63);
        *(bf16x4*)&Vt[(((size_t)b * 16 + h) * 64 + d) * 2048 + s2] = o;
      }
    }
  }
}

// ---------------------------------------------------------------------------
// Kernel 2b (out-proj): C(MxN) = A(MxK) @ B(NxK)^T, fp32 out.
// BK=64 + both-sides-swizzle structure (r19, unchanged).
// ---------------------------------------------------------------------------
template <typename OutT, int BM, int BN>
__global__ __launch_bounds__(256) void gemm_bt(
    const bf16* __restrict__ A, const bf16* __restrict__ B,
    OutT* __restrict__ C, int M, int N, int K) {
  constexpr int FM = BM / 32, FN = BN / 32;
  constexpr int SA = BM / 32, SB = BN / 32;
  __shared__ __align__(16) bf16 As[BM * 64];
  __shared__ __align__(16) bf16 Bs[BN * 64];
  const int tid = threadIdx.x;
  const int wave = tid >> 6, lane = tid & 63;
  const int bm = blockIdx.y * BM, bn = blockIdx.x * BN;
  const int wm = (wave >> 1) * (BM / 2), wn = (wave & 1) * (BN / 2);
  const int fr = lane & 15, g = lane >> 4;
  const int sw8 = (fr & 7) * 8;
  const int srow = tid >> 3;
  const int scol = 8 * ((tid & 7) ^ (srow & 7));
  const int ldst = wave * 512;

  f32x4 acc[FM][FN] = {};

  for (int kt = 0; kt < K; kt += 64) {
    __syncthreads();
#pragma unroll
    for (int s = 0; s < SA; ++s)
      async_load16(A + (size_t)(bm + s * 32 + srow) * K + kt + scol,
                   (void*)(As + s * 2048 + ldst));
#pragma unroll
    for (int s = 0; s < SB; ++s)
      async_load16(B + (size_t)(bn + s * 32 + srow) * K + kt + scol,
                   (void*)(Bs + s * 2048 + ldst));
    __syncthreads();

#pragma unroll
    for (int ks = 0; ks < 2; ++ks) {
      const int kq = (ks * 32 + g * 8) ^ sw8;
      bf16x8 af[FM], bfr[FN];
#pragma unroll
      for (int i = 0; i < FM; ++i)
        af[i] = *(const bf16x8*)&As[(wm + i * 16 + fr) * 64 + kq];
#pragma unroll
      for (int j = 0; j < FN; ++j)
        bfr[j] = *(const bf16x8*)&Bs[(wn + j * 16 + fr) * 64 + kq];
#pragma unroll
      for (int i = 0; i < FM; ++i)
#pragma unroll
        for (int j = 0; j < FN; ++j)
          acc[i][j] = __builtin_amdgcn_mfma_f32_16x16x32_bf16(af[i], bfr[j],
                                                              acc[i][j], 0, 0, 0);
    }
  }

  const int r0 = (lane >> 4) * 4, cc = lane & 15;
#pragma unroll
  for (int i = 0; i < FM; ++i)
#pragma unroll
    for (int j = 0; j < FN; ++j)
#pragma unroll
      for (int r = 0; r < 4; ++r)
        C[(size_t)(bm + wm + i * 16 + r0 + r) * N + (bn + wn + j * 16 + cc)] =
            (OutT)acc[i][j][r];
}

// ---------------------------------------------------------------------------
// Kernel 3: causal attention — ROUND 23: grid-level TLP.
// r22 post-mortem: pipeline spilled (WRITE 8->25MB scratch signature) ->
// reverted to the r21 serial body. r21 post-mortem recount: 1024 blocks x
// 2 waves = only 8 waves/CU LAUNCHED — the occupancy ceiling was the GRID,
// never registers/LDS. Every structure since r16 ran at <=2 waves/SIMD.
// Fix: 2048 blocks x 128 thr = 4096 waves = 16/CU launched = 4/SIMD.
//   * block = ONE 32-row q-tile; 2 waves split its k-range (r21-verified
//     additive unnormalized exp2; combine = 2 end barriers via LDS).
//   * footprint trimmed for 4 waves/SIMD residency: single pk buffer
//     (ldK(i+1) issued after QK(i) consumed it), single V slot/wave
//     (16KB/block -> 8 blocks/CU), st[4] reused per qb, ~120 unified regs,
//     __launch_bounds__(128,4).
//   * serial body (QK->exp->PV) ON PURPOSE: the bet is TLP over ILP —
//     exposed per-iter latency (~800cy) interleaves across 4 waves/SIMD.
//   * LPT (qt=63 first) + bh=f&31 XCD affinity retained.
// Decision rule: occupancy >=35% but dur >=45us -> wall is shared L2/LDS
// BW, stop restructuring attn.
// ---------------------------------------------------------------------------
__global__ __launch_bounds__(128, 4) void attn(const bf16* __restrict__ Qh,
                                               const bf16* __restrict__ Kh,
                                               const bf16* __restrict__ Vt,
                                               bf16* __restrict__ Oh) {
  __shared__ __align__(16) bf16 Vs[2][4096];  // per-wave single slot, 16 KB
  const int f = blockIdx.x;
  const int qt = 63 - (f >> 5);  // LPT: longest q-tiles dispatch first
  const int bh = f & 31;         // bh%8 == f%8 -> XCD affinity (4 bh/XCD)
  const int tid = threadIdx.x, w = tid >> 6, lane = tid & 63;
  const int nlo = lane & 15, g = lane >> 4;
  const int q0 = qt * 32;
  const bf16* __restrict__ Qp = Qh + (size_t)bh * 131072;
  const bf16* __restrict__ Kp = Kh + (size_t)bh * 131072;
  const bf16* __restrict__ Vp = Vt + (size_t)bh * 131072;
  const int n = (qt >> 1) + 1;   // k-tiles for this q-tile
  const int h = (n + 1) >> 1;    // wave0: [0,h), wave1: [h,n)
  const int t0 = w ? h : 0;
  const int cnt = w ? (n - h) : h;
  const int bb = bh >> 4, hd = bh & 15;
  const int sw = (nlo & 7) << 3;                      // inverse V-swizzle
  const int srow = lane >> 3, soff = (lane & 7) * 8;  // V staging geometry
  bf16* __restrict__ Vw = Vs[w];

  // Q fragments (B-operand: n=q=nlo, k=d)
  bf16x8 aq[2][2];
#pragma unroll
  for (int qb = 0; qb < 2; ++qb)
#pragma unroll
    for (int ks = 0; ks < 2; ++ks)
      aq[qb][ks] = *(const bf16x8*)&Qp[(size_t)(q0 + qb * 16 + nlo) * 64 +
                                       ks * 32 + g * 8];

  f32x4 oacc[2][4] = {};  // O^T C-layout (m=d, n=q)
  float lsum[2] = {0.f, 0.f};
  bf16x8 pk[4][2];  // K fragments, single buffer

  auto ldK = [&](int i) {
#pragma unroll
    for (int ni = 0; ni < 4; ++ni)
#pragma unroll
      for (int ks = 0; ks < 2; ++ks)
        pk[ni][ks] = *(const bf16x8*)&Kp[(size_t)(i * 64 + ni * 16 + nlo) * 64 +
                                         ks * 32 + g * 8];
  };
  auto stageV = [&](int i) {
    const bf16* src = Vp + (size_t)srow * 2048 + i * 64 + soff;
#pragma unroll
    for (int c = 0; c < 8; ++c)
      async_load16(src + (size_t)c * 16384, (void*)(Vw + c * 512));
  };

  if (cnt > 0) {
    ldK(t0);
    stageV(t0);
  }

  for (int it = 0; it < cnt; ++it) {
    const int i = t0 + it, kbase = i * 64;
    asm volatile("s_waitcnt vmcnt(0)" ::: "memory");  // K(i)+V(i) landed
    const bool dg = (i == n - 1);  // diagonal tile (wave-uniform)
    bf16x4 p[2][4];
#pragma unroll
    for (int qb = 0; qb < 2; ++qb) {
      f32x4 st[4] = {};
#pragma unroll
      for (int ks = 0; ks < 2; ++ks)
#pragma unroll
        for (int ni = 0; ni < 4; ++ni)
          st[ni] = __builtin_amdgcn_mfma_f32_16x16x32_bf16(pk[ni][ks], aq[qb][ks],
                                                           st[ni], 0, 0, 0);
      const int qg = q0 + qb * 16 + nlo;
      if (!dg) {
#pragma unroll
        for (int ni = 0; ni < 4; ++ni)
#pragma unroll
          for (int r = 0; r < 4; ++r) {
            float e = __builtin_amdgcn_exp2f(st[ni][r]);
            lsum[qb] += e;
            p[qb][ni][r] = (bf16)e;
          }
      } else {
#pragma unroll
        for (int ni = 0; ni < 4; ++ni) {
          const int kg0 = kbase + ni * 16 + g * 4;
#pragma unroll
          for (int r = 0; r < 4; ++r) {
            float e = __builtin_amdgcn_exp2f(st[ni][r]);
            e = (kg0 + r <= qg) ? e : 0.0f;
            lsum[qb] += e;
            p[qb][ni][r] = (bf16)e;
          }
        }
      }
    }
    // pk fully consumed -> prefetch K(i+1) (distance: PV + loop edge)
    if (it + 1 < cnt) ldK(i + 1);
    // O^T += V^T.P
#pragma unroll
    for (int ni = 0; ni < 4; ++ni)
#pragma unroll
      for (int mi = 0; mi < 4; ++mi) {
        bf16x4 av = *(const bf16x4*)&Vw[(mi * 16 + nlo) * 64 +
                                        ((ni * 16 + g * 4) ^ sw)];
#pragma unroll
        for (int qb = 0; qb < 2; ++qb)
          oacc[qb][mi] = mfma16(av, p[qb][ni], oacc[qb][mi]);
      }
    // V reads retired (MFMA operand deps) -> safe to overwrite the slot
    if (it + 1 < cnt) {
      asm volatile("s_waitcnt lgkmcnt(0)" ::: "memory");
      stageV(i + 1);
    }
  }

  // finish l: reduce over the 4 g-groups (columns are per-nlo)
#pragma unroll
  for (int qb = 0; qb < 2; ++qb) {
    lsum[qb] += __shfl_xor(lsum[qb], 16, 64);
    lsum[qb] += __shfl_xor(lsum[qb], 32, 64);
  }

  // combine: wave1 -> LDS (slots now dead), wave0 adds + writes
  float* __restrict__ scr = (float*)Vs[1];  // 2048 floats = wave1 slot
  float* __restrict__ scl = (float*)Vs[0];  // lsum scratch in wave0 slot
  __syncthreads();
  if (w == 1) {
#pragma unroll
    for (int qb = 0; qb < 2; ++qb) {
#pragma unroll
      for (int mi = 0; mi < 4; ++mi)
#pragma unroll
        for (int r = 0; r < 4; ++r)
          scr[(qb * 16 + mi * 4 + r) * 64 + lane] = oacc[qb][mi][r];
      scl[qb * 64 + lane] = lsum[qb];
    }
  }
  __syncthreads();
  if (w == 0) {
#pragma unroll
    for (int qb = 0; qb < 2; ++qb) {
      const float l = lsum[qb] + scl[qb * 64 + lane];
      const float inv = 1.0f / l;
      const int q = q0 + qb * 16 + nlo;
#pragma unroll
      for (int mi = 0; mi < 4; ++mi) {
        bf16x4 o;
#pragma unroll
        for (int r = 0; r < 4; ++r)
          o[r] = (bf16)((oacc[qb][mi][r] +
                         scr[(qb * 16 + mi * 4 + r) * 64 + lane]) * inv);
        *(bf16x4*)&Oh[((size_t)bb * 2048 + q) * 1024 + hd * 64 + mi * 16 +
                      g * 4] = o;
      }
    }
  }
}

// ---------------------------------------------------------------------------
extern "C" void kernel_launch(void* const* d_in, const int* in_sizes, int n_in,
                              void* d_out, int out_size, void* d_ws, size_t ws_size,
                              hipStream_t stream) {
  (void)in_sizes; (void)n_in; (void)out_size; (void)ws_size;
  const float* x = (const float*)d_in[0];
  const float* Wq = (const float*)d_in[1];
  const float* Wk = (const float*)d_in[2];
  const float* Wv = (const float*)d_in[3];
  const float* Wo = (const float*)d_in[4];
  float* out = (float*)d_out;
  char* ws = (char*)d_ws;

  bf16* Xh    = (bf16*)(ws);                 // 4096x1024          8 MB
  bf16* Wqkv  = (bf16*)(ws + 8388608);       // 3072x1024          6 MB
  bf16* Woh   = (bf16*)(ws + 14680064);      // 1024x1024          2 MB
  bf16* Qh    = (bf16*)(ws + 16777216);      // [32][2048][64]     8 MB
  bf16* Kh    = (bf16*)(ws + 25165824);      // [32][2048][64]     8 MB (linear)
  bf16* Vt    = (bf16*)(ws + 33554432);      // [32][64][2048]     8 MB (col-swizzled)
  bf16* Oh    = (bf16*)(ws + 41943040);      // 4096x1024          8 MB
  float2* rope = (float2*)(ws + 50331648);   // [2048][32] cos/sin 512 KB

  cast_all<<<8256, 256, 0, stream>>>(x, Wq, Wk, Wv, Wo, Xh, Wqkv, Woh, rope);
  gemm_qkv<<<dim3(24, 32), 256, 0, stream>>>(Xh, Wqkv, rope, Qh, Kh, Vt, 1024);
  attn<<<2048, 128, 0, stream>>>(Qh, Kh, Vt, Oh);
  gemm_bt<float, 128, 128><<<dim3(8, 32), 256, 0, stream>>>(Oh, Woh, out, 4096, 1024, 1024);
}

// Round 11
// 185.979 us; speedup vs baseline: 1.1406x; 1.1406x over previous
//
#include <hip/hip_runtime.h>
#include <stdint.h>
#include <stddef.h>

typedef __bf16 bf16;
typedef __bf16 bf16x8 __attribute__((ext_vector_type(8)));
typedef __bf16 bf16x4 __attribute__((ext_vector_type(4)));
typedef short short4v __attribute__((ext_vector_type(4)));
typedef float f32x4 __attribute__((ext_vector_type(4)));

#define GAS __attribute__((address_space(1)))
#define LAS __attribute__((address_space(3)))

__device__ __forceinline__ void async_load16(const void* g, void* l) {
  __builtin_amdgcn_global_load_lds((const GAS void*)g, (LAS void*)l, 16, 0, 0);
}

// 16x16x16 bf16 MFMA. C-layout of a 16x16 MFMA == B-layout of this shape,
// so P^T feeds PV straight from registers. Host pass gets a stub.
__device__ __forceinline__ f32x4 mfma16(bf16x4 a, bf16x4 b, f32x4 c) {
#if defined(__HIP_DEVICE_COMPILE__)
#if __has_builtin(__builtin_amdgcn_mfma_f32_16x16x16bf16_1k)
  return __builtin_amdgcn_mfma_f32_16x16x16bf16_1k(
      __builtin_bit_cast(short4v, a), __builtin_bit_cast(short4v, b), c, 0, 0, 0);
#else
  f32x4 d;
  asm volatile("v_mfma_f32_16x16x16_bf16 %0, %1, %2, %3"
               : "=v"(d)
               : "v"(a), "v"(b), "v"(c));
  return d;
#endif
#else
  (void)a; (void)b;
  return c;
#endif
}

// ---------------------------------------------------------------------------
// Kernel 1: fp32 -> bf16 casts, x4 vectorized. Wq pre-scaled by 0.125*log2(e)
// so QK^T lands in the exp2 domain. Blocks >= 8192 build the RoPE cos/sin
// table rope[s][ip] (float2, 2048x32 = 512KB).
// ---------------------------------------------------------------------------
__global__ __launch_bounds__(256) void cast_all(
    const float* __restrict__ x, const float* __restrict__ Wq,
    const float* __restrict__ Wk, const float* __restrict__ Wv,
    const float* __restrict__ Wo, bf16* __restrict__ Xh,
    bf16* __restrict__ Wqkv, bf16* __restrict__ Woh,
    float2* __restrict__ rope) {
  if (blockIdx.x >= 8192) {
    const int e = ((blockIdx.x - 8192) * 256 + threadIdx.x) * 4;
    const int s = e >> 5, ip0 = e & 31;
#pragma unroll
    for (int r = 0; r < 4; ++r) {
      const float freq = __expf((float)(ip0 + r) * -0.2878231366242557f);
      float sn, cs;
      __sincosf((float)s * freq, &sn, &cs);
      rope[e + r] = make_float2(cs, sn);
    }
    return;
  }
  int idx = (blockIdx.x * 256 + threadIdx.x) * 4;
  const float* src;
  bf16* dst;
  float scale = 1.0f;
  if (idx < 4194304) {
    src = x + idx; dst = Xh + idx;
  } else if (idx < 7340032) {
    int j = idx - 4194304;
    if (j < 1048576) {
      src = Wq + j; scale = 0.18033688011112042f;
    } else {
      src = ((j < 2097152) ? Wk : Wv) + (j & 1048575);
    }
    dst = Wqkv + j;
  } else {
    int j = idx - 7340032;
    src = Wo + j; dst = Woh + j;
  }
  float4 v = *(const float4*)src;
  bf16x4 o;
  o[0] = (bf16)(v.x * scale); o[1] = (bf16)(v.y * scale);
  o[2] = (bf16)(v.z * scale); o[3] = (bf16)(v.w * scale);
  *(bf16x4*)dst = o;
}

// ---------------------------------------------------------------------------
// Kernel 2: QKV projection with FUSED RoPE + V-transpose epilogue.
// BK=64 + both-sides XOR swizzle in the main loop (r18, verified).
// Q -> Qh linear; K -> Kh linear; V -> Vt col-swizzled (attn LDS path).
// ---------------------------------------------------------------------------
__global__ __launch_bounds__(256, 3) void gemm_qkv(
    const bf16* __restrict__ A, const bf16* __restrict__ B,
    const float2* __restrict__ rope, bf16* __restrict__ Qh,
    bf16* __restrict__ Kh, bf16* __restrict__ Vt, int K) {
  __shared__ __align__(16) bf16 As[128 * 64];
  __shared__ __align__(16) bf16 Bs[128 * 64];
  const int tid = threadIdx.x;
  const int wave = tid >> 6, lane = tid & 63;
  const int bm = blockIdx.y * 128, bn = blockIdx.x * 128;
  const int wm = (wave >> 1) * 64, wn = (wave & 1) * 64;
  const int fr = lane & 15, g = lane >> 4;
  const int sw8 = (fr & 7) * 8;  // read-side swizzle

  const int srow = tid >> 3;
  const int scol = 8 * ((tid & 7) ^ (srow & 7));
  const int ldst = wave * 512;

  f32x4 acc[4][4] = {};

  for (int kt = 0; kt < K; kt += 64) {
    __syncthreads();
#pragma unroll
    for (int s = 0; s < 4; ++s) {
      const int row = s * 32 + srow;
      async_load16(A + (size_t)(bm + row) * K + kt + scol,
                   (void*)(As + s * 2048 + ldst));
      async_load16(B + (size_t)(bn + row) * K + kt + scol,
                   (void*)(Bs + s * 2048 + ldst));
    }
    __syncthreads();

#pragma unroll
    for (int ks = 0; ks < 2; ++ks) {
      bf16x8 af[4], bfr[4];
      const int kq = (ks * 32 + g * 8) ^ sw8;
#pragma unroll
      for (int i = 0; i < 4; ++i)
        af[i] = *(const bf16x8*)&As[(wm + i * 16 + fr) * 64 + kq];
#pragma unroll
      for (int j = 0; j < 4; ++j)
        bfr[j] = *(const bf16x8*)&Bs[(wn + j * 16 + fr) * 64 + kq];
#pragma unroll
      for (int i = 0; i < 4; ++i)
#pragma unroll
        for (int j = 0; j < 4; ++j)
          acc[i][j] = __builtin_amdgcn_mfma_f32_16x16x32_bf16(af[i], bfr[j],
                                                              acc[i][j], 0, 0, 0);
    }
  }

  const int r0 = (lane >> 4) * 4, cc = lane & 15;
  const bool oddl = cc & 1;
#pragma unroll
  for (int i = 0; i < 4; ++i) {
    const int row0 = bm + wm + i * 16 + r0;
    const int b = row0 >> 11, s0 = row0 & 2047;
#pragma unroll
    for (int j = 0; j < 4; ++j) {
      const int col = bn + wn + j * 16 + cc;  // whole wave same region per j
      if (col < 2048) {
        // RoPE: pair partner is lane^1 (col 2k <-> 2k+1)
        const int hcol = col & 1023;
        const int h = hcol >> 6, d = hcol & 63;
        const int ip = d >> 1;
        const bool isK = col >= 1024;
        bf16* dst = (isK ? Kh : Qh) + ((size_t)(b * 16 + h) * 2048) * 64;
#pragma unroll
        for (int r = 0; r < 4; ++r) {
          float own = acc[i][j][r];
          float oth = __shfl_xor(own, 1, 64);
          const float2 t = rope[((s0 + r) << 5) + ip];
          float res = oddl ? (oth * t.y + own * t.x) : (own * t.x - oth * t.y);
          dst[(size_t)(s0 + r) * 64 + d] = (bf16)res;
        }
      } else {
        const int v = col - 2048, h = v >> 6, d = v & 63;
        bf16x4 o;
#pragma unroll
        for (int r = 0; r < 4; ++r) o[r] = (bf16)acc[i][j][r];
        // col-swizzled within each 64-wide tile (verified r18/r19); 4-run
        // at s0 stays contiguous (XOR touches bits 3..5, s0 is 4-aligned)
        const int s2 = (s0 & ~63) | ((s0 ^ ((d & 7) << 3)) & 63);
        *(bf16x4*)&Vt[(((size_t)b * 16 + h) * 64 + d) * 2048 + s2] = o;
      }
    }
  }
}

// ---------------------------------------------------------------------------
// Kernel 2b (out-proj): C(MxN) = A(MxK) @ B(NxK)^T, fp32 out.
// BK=64 + both-sides-swizzle structure (r19, unchanged).
// ---------------------------------------------------------------------------
template <typename OutT, int BM, int BN>
__global__ __launch_bounds__(256) void gemm_bt(
    const bf16* __restrict__ A, const bf16* __restrict__ B,
    OutT* __restrict__ C, int M, int N, int K) {
  constexpr int FM = BM / 32, FN = BN / 32;
  constexpr int SA = BM / 32, SB = BN / 32;
  __shared__ __align__(16) bf16 As[BM * 64];
  __shared__ __align__(16) bf16 Bs[BN * 64];
  const int tid = threadIdx.x;
  const int wave = tid >> 6, lane = tid & 63;
  const int bm = blockIdx.y * BM, bn = blockIdx.x * BN;
  const int wm = (wave >> 1) * (BM / 2), wn = (wave & 1) * (BN / 2);
  const int fr = lane & 15, g = lane >> 4;
  const int sw8 = (fr & 7) * 8;
  const int srow = tid >> 3;
  const int scol = 8 * ((tid & 7) ^ (srow & 7));
  const int ldst = wave * 512;

  f32x4 acc[FM][FN] = {};

  for (int kt = 0; kt < K; kt += 64) {
    __syncthreads();
#pragma unroll
    for (int s = 0; s < SA; ++s)
      async_load16(A + (size_t)(bm + s * 32 + srow) * K + kt + scol,
                   (void*)(As + s * 2048 + ldst));
#pragma unroll
    for (int s = 0; s < SB; ++s)
      async_load16(B + (size_t)(bn + s * 32 + srow) * K + kt + scol,
                   (void*)(Bs + s * 2048 + ldst));
    __syncthreads();

#pragma unroll
    for (int ks = 0; ks < 2; ++ks) {
      const int kq = (ks * 32 + g * 8) ^ sw8;
      bf16x8 af[FM], bfr[FN];
#pragma unroll
      for (int i = 0; i < FM; ++i)
        af[i] = *(const bf16x8*)&As[(wm + i * 16 + fr) * 64 + kq];
#pragma unroll
      for (int j = 0; j < FN; ++j)
        bfr[j] = *(const bf16x8*)&Bs[(wn + j * 16 + fr) * 64 + kq];
#pragma unroll
      for (int i = 0; i < FM; ++i)
#pragma unroll
        for (int j = 0; j < FN; ++j)
          acc[i][j] = __builtin_amdgcn_mfma_f32_16x16x32_bf16(af[i], bfr[j],
                                                              acc[i][j], 0, 0, 0);
    }
  }

  const int r0 = (lane >> 4) * 4, cc = lane & 15;
#pragma unroll
  for (int i = 0; i < FM; ++i)
#pragma unroll
    for (int j = 0; j < FN; ++j)
#pragma unroll
      for (int r = 0; r < 4; ++r)
        C[(size_t)(bm + wm + i * 16 + r0 + r) * N + (bn + wn + j * 16 + cc)] =
            (OutT)acc[i][j][r];
}

// ---------------------------------------------------------------------------
// Kernel 3: causal attention — ROUND 24: r23 structure, spill fixed.
// r23 post-mortem: __launch_bounds__(128,4) caps unified regs at 128; body
// needs ~140-150 -> compiler spilled (WRITE 8->43MB scratch signature),
// 79us. But occupancy DID reach 28% — the 2048-block grid delivers
// residency. This round changes ONLY the bound: (128,4) -> (128,3), cap
// 170 regs (r21's superset body measured 104, fits with room). 3 waves/
// SIMD resident, serial body, TLP-over-ILP bet now actually measurable.
// Decision rule: spill counters normalize but attn >= 45us -> TLP theory
// dead, attn at structural limit, move to the projection kernels.
// ---------------------------------------------------------------------------
__global__ __launch_bounds__(128, 3) void attn(const bf16* __restrict__ Qh,
                                               const bf16* __restrict__ Kh,
                                               const bf16* __restrict__ Vt,
                                               bf16* __restrict__ Oh) {
  __shared__ __align__(16) bf16 Vs[2][4096];  // per-wave single slot, 16 KB
  const int f = blockIdx.x;
  const int qt = 63 - (f >> 5);  // LPT: longest q-tiles dispatch first
  const int bh = f & 31;         // bh%8 == f%8 -> XCD affinity (4 bh/XCD)
  const int tid = threadIdx.x, w = tid >> 6, lane = tid & 63;
  const int nlo = lane & 15, g = lane >> 4;
  const int q0 = qt * 32;
  const bf16* __restrict__ Qp = Qh + (size_t)bh * 131072;
  const bf16* __restrict__ Kp = Kh + (size_t)bh * 131072;
  const bf16* __restrict__ Vp = Vt + (size_t)bh * 131072;
  const int n = (qt >> 1) + 1;   // k-tiles for this q-tile
  const int h = (n + 1) >> 1;    // wave0: [0,h), wave1: [h,n)
  const int t0 = w ? h : 0;
  const int cnt = w ? (n - h) : h;
  const int bb = bh >> 4, hd = bh & 15;
  const int sw = (nlo & 7) << 3;                      // inverse V-swizzle
  const int srow = lane >> 3, soff = (lane & 7) * 8;  // V staging geometry
  bf16* __restrict__ Vw = Vs[w];

  // Q fragments (B-operand: n=q=nlo, k=d)
  bf16x8 aq[2][2];
#pragma unroll
  for (int qb = 0; qb < 2; ++qb)
#pragma unroll
    for (int ks = 0; ks < 2; ++ks)
      aq[qb][ks] = *(const bf16x8*)&Qp[(size_t)(q0 + qb * 16 + nlo) * 64 +
                                       ks * 32 + g * 8];

  f32x4 oacc[2][4] = {};  // O^T C-layout (m=d, n=q)
  float lsum[2] = {0.f, 0.f};
  bf16x8 pk[4][2];  // K fragments, single buffer

  auto ldK = [&](int i) {
#pragma unroll
    for (int ni = 0; ni < 4; ++ni)
#pragma unroll
      for (int ks = 0; ks < 2; ++ks)
        pk[ni][ks] = *(const bf16x8*)&Kp[(size_t)(i * 64 + ni * 16 + nlo) * 64 +
                                         ks * 32 + g * 8];
  };
  auto stageV = [&](int i) {
    const bf16* src = Vp + (size_t)srow * 2048 + i * 64 + soff;
#pragma unroll
    for (int c = 0; c < 8; ++c)
      async_load16(src + (size_t)c * 16384, (void*)(Vw + c * 512));
  };

  if (cnt > 0) {
    ldK(t0);
    stageV(t0);
  }

  for (int it = 0; it < cnt; ++it) {
    const int i = t0 + it, kbase = i * 64;
    asm volatile("s_waitcnt vmcnt(0)" ::: "memory");  // K(i)+V(i) landed
    const bool dg = (i == n - 1);  // diagonal tile (wave-uniform)
    bf16x4 p[2][4];
#pragma unroll
    for (int qb = 0; qb < 2; ++qb) {
      f32x4 st[4] = {};
#pragma unroll
      for (int ks = 0; ks < 2; ++ks)
#pragma unroll
        for (int ni = 0; ni < 4; ++ni)
          st[ni] = __builtin_amdgcn_mfma_f32_16x16x32_bf16(pk[ni][ks], aq[qb][ks],
                                                           st[ni], 0, 0, 0);
      const int qg = q0 + qb * 16 + nlo;
      if (!dg) {
#pragma unroll
        for (int ni = 0; ni < 4; ++ni)
#pragma unroll
          for (int r = 0; r < 4; ++r) {
            float e = __builtin_amdgcn_exp2f(st[ni][r]);
            lsum[qb] += e;
            p[qb][ni][r] = (bf16)e;
          }
      } else {
#pragma unroll
        for (int ni = 0; ni < 4; ++ni) {
          const int kg0 = kbase + ni * 16 + g * 4;
#pragma unroll
          for (int r = 0; r < 4; ++r) {
            float e = __builtin_amdgcn_exp2f(st[ni][r]);
            e = (kg0 + r <= qg) ? e : 0.0f;
            lsum[qb] += e;
            p[qb][ni][r] = (bf16)e;
          }
        }
      }
    }
    // pk fully consumed -> prefetch K(i+1) (distance: PV + loop edge)
    if (it + 1 < cnt) ldK(i + 1);
    // O^T += V^T.P
#pragma unroll
    for (int ni = 0; ni < 4; ++ni)
#pragma unroll
      for (int mi = 0; mi < 4; ++mi) {
        bf16x4 av = *(const bf16x4*)&Vw[(mi * 16 + nlo) * 64 +
                                        ((ni * 16 + g * 4) ^ sw)];
#pragma unroll
        for (int qb = 0; qb < 2; ++qb)
          oacc[qb][mi] = mfma16(av, p[qb][ni], oacc[qb][mi]);
      }
    // V reads retired (MFMA operand deps) -> safe to overwrite the slot
    if (it + 1 < cnt) {
      asm volatile("s_waitcnt lgkmcnt(0)" ::: "memory");
      stageV(i + 1);
    }
  }

  // finish l: reduce over the 4 g-groups (columns are per-nlo)
#pragma unroll
  for (int qb = 0; qb < 2; ++qb) {
    lsum[qb] += __shfl_xor(lsum[qb], 16, 64);
    lsum[qb] += __shfl_xor(lsum[qb], 32, 64);
  }

  // combine: wave1 -> LDS (slots now dead), wave0 adds + writes
  float* __restrict__ scr = (float*)Vs[1];  // 2048 floats = wave1 slot
  float* __restrict__ scl = (float*)Vs[0];  // lsum scratch in wave0 slot
  __syncthreads();
  if (w == 1) {
#pragma unroll
    for (int qb = 0; qb < 2; ++qb) {
#pragma unroll
      for (int mi = 0; mi < 4; ++mi)
#pragma unroll
        for (int r = 0; r < 4; ++r)
          scr[(qb * 16 + mi * 4 + r) * 64 + lane] = oacc[qb][mi][r];
      scl[qb * 64 + lane] = lsum[qb];
    }
  }
  __syncthreads();
  if (w == 0) {
#pragma unroll
    for (int qb = 0; qb < 2; ++qb) {
      const float l = lsum[qb] + scl[qb * 64 + lane];
      const float inv = 1.0f / l;
      const int q = q0 + qb * 16 + nlo;
#pragma unroll
      for (int mi = 0; mi < 4; ++mi) {
        bf16x4 o;
#pragma unroll
        for (int r = 0; r < 4; ++r)
          o[r] = (bf16)((oacc[qb][mi][r] +
                         scr[(qb * 16 + mi * 4 + r) * 64 + lane]) * inv);
        *(bf16x4*)&Oh[((size_t)bb * 2048 + q) * 1024 + hd * 64 + mi * 16 +
                      g * 4] = o;
      }
    }
  }
}

// ---------------------------------------------------------------------------
extern "C" void kernel_launch(void* const* d_in, const int* in_sizes, int n_in,
                              void* d_out, int out_size, void* d_ws, size_t ws_size,
                              hipStream_t stream) {
  (void)in_sizes; (void)n_in; (void)out_size; (void)ws_size;
  const float* x = (const float*)d_in[0];
  const float* Wq = (const float*)d_in[1];
  const float* Wk = (const float*)d_in[2];
  const float* Wv = (const float*)d_in[3];
  const float* Wo = (const float*)d_in[4];
  float* out = (float*)d_out;
  char* ws = (char*)d_ws;

  bf16* Xh    = (bf16*)(ws);                 // 4096x1024          8 MB
  bf16* Wqkv  = (bf16*)(ws + 8388608);       // 3072x1024          6 MB
  bf16* Woh   = (bf16*)(ws + 14680064);      // 1024x1024          2 MB
  bf16* Qh    = (bf16*)(ws + 16777216);      // [32][2048][64]     8 MB
  bf16* Kh    = (bf16*)(ws + 25165824);      // [32][2048][64]     8 MB (linear)
  bf16* Vt    = (bf16*)(ws + 33554432);      // [32][64][2048]     8 MB (col-swizzled)
  bf16* Oh    = (bf16*)(ws + 41943040);      // 4096x1024          8 MB
  float2* rope = (float2*)(ws + 50331648);   // [2048][32] cos/sin 512 KB

  cast_all<<<8256, 256, 0, stream>>>(x, Wq, Wk, Wv, Wo, Xh, Wqkv, Woh, rope);
  gemm_qkv<<<dim3(24, 32), 256, 0, stream>>>(Xh, Wqkv, rope, Qh, Kh, Vt, 1024);
  attn<<<2048, 128, 0, stream>>>(Qh, Kh, Vt, Oh);
  gemm_bt<float, 128, 128><<<dim3(8, 32), 256, 0, stream>>>(Oh, Woh, out, 4096, 1024, 1024);
}

// Round 12
// 182.758 us; speedup vs baseline: 1.1607x; 1.0176x over previous
//
#include <hip/hip_runtime.h>
#include <stdint.h>
#include <stddef.h>

typedef __bf16 bf16;
typedef __bf16 bf16x8 __attribute__((ext_vector_type(8)));
typedef __bf16 bf16x4 __attribute__((ext_vector_type(4)));
typedef short short4v __attribute__((ext_vector_type(4)));
typedef float f32x4 __attribute__((ext_vector_type(4)));

#define GAS __attribute__((address_space(1)))
#define LAS __attribute__((address_space(3)))

__device__ __forceinline__ void async_load16(const void* g, void* l) {
  __builtin_amdgcn_global_load_lds((const GAS void*)g, (LAS void*)l, 16, 0, 0);
}

// 16x16x16 bf16 MFMA. C-layout of a 16x16 MFMA == B-layout of this shape,
// so P^T feeds PV straight from registers. Host pass gets a stub.
__device__ __forceinline__ f32x4 mfma16(bf16x4 a, bf16x4 b, f32x4 c) {
#if defined(__HIP_DEVICE_COMPILE__)
#if __has_builtin(__builtin_amdgcn_mfma_f32_16x16x16bf16_1k)
  return __builtin_amdgcn_mfma_f32_16x16x16bf16_1k(
      __builtin_bit_cast(short4v, a), __builtin_bit_cast(short4v, b), c, 0, 0, 0);
#else
  f32x4 d;
  asm volatile("v_mfma_f32_16x16x16_bf16 %0, %1, %2, %3"
               : "=v"(d)
               : "v"(a), "v"(b), "v"(c));
  return d;
#endif
#else
  (void)a; (void)b;
  return c;
#endif
}

// ---------------------------------------------------------------------------
// Kernel 1: fp32 -> bf16 casts, x4 vectorized. Wq pre-scaled by 0.125*log2(e)
// so QK^T lands in the exp2 domain. Blocks >= 8192 build the RoPE cos/sin
// table rope[s][ip] (float2, 2048x32 = 512KB).
// ---------------------------------------------------------------------------
__global__ __launch_bounds__(256) void cast_all(
    const float* __restrict__ x, const float* __restrict__ Wq,
    const float* __restrict__ Wk, const float* __restrict__ Wv,
    const float* __restrict__ Wo, bf16* __restrict__ Xh,
    bf16* __restrict__ Wqkv, bf16* __restrict__ Woh,
    float2* __restrict__ rope) {
  if (blockIdx.x >= 8192) {
    // RoPE table: entry e -> s = e>>5, ip = e&31 (4 per thread, same s).
    const int e = ((blockIdx.x - 8192) * 256 + threadIdx.x) * 4;
    const int s = e >> 5, ip0 = e & 31;
#pragma unroll
    for (int r = 0; r < 4; ++r) {
      const float freq = __expf((float)(ip0 + r) * -0.2878231366242557f);
      float sn, cs;
      __sincosf((float)s * freq, &sn, &cs);
      rope[e + r] = make_float2(cs, sn);
    }
    return;
  }
  int idx = (blockIdx.x * 256 + threadIdx.x) * 4;
  const float* src;
  bf16* dst;
  float scale = 1.0f;
  if (idx < 4194304) {
    src = x + idx; dst = Xh + idx;
  } else if (idx < 7340032) {
    int j = idx - 4194304;
    if (j < 1048576) {
      src = Wq + j; scale = 0.18033688011112042f;
    } else {
      src = ((j < 2097152) ? Wk : Wv) + (j & 1048575);
    }
    dst = Wqkv + j;
  } else {
    int j = idx - 7340032;
    src = Wo + j; dst = Woh + j;
  }
  float4 v = *(const float4*)src;
  bf16x4 o;
  o[0] = (bf16)(v.x * scale); o[1] = (bf16)(v.y * scale);
  o[2] = (bf16)(v.z * scale); o[3] = (bf16)(v.w * scale);
  *(bf16x4*)dst = o;
}

// ---------------------------------------------------------------------------
// Kernel 2: QKV projection with FUSED RoPE + V-transpose epilogue.
// BK=64 + both-sides XOR swizzle (r18 structure, verified: 63us -> <43us).
// ROUND 25 (revert to r19 outputs): Q -> Qh linear; K -> Kh d-swizzled
// (d ^ ((s&7)<<3)) for attn's LDS staging path; V -> Vt col-swizzled.
// ---------------------------------------------------------------------------
__global__ __launch_bounds__(256, 3) void gemm_qkv(
    const bf16* __restrict__ A, const bf16* __restrict__ B,
    const float2* __restrict__ rope, bf16* __restrict__ Qh,
    bf16* __restrict__ Kh, bf16* __restrict__ Vt, int K) {
  __shared__ __align__(16) bf16 As[128 * 64];
  __shared__ __align__(16) bf16 Bs[128 * 64];
  const int tid = threadIdx.x;
  const int wave = tid >> 6, lane = tid & 63;
  const int bm = blockIdx.y * 128, bn = blockIdx.x * 128;
  const int wm = (wave >> 1) * 64, wn = (wave & 1) * 64;
  const int fr = lane & 15, g = lane >> 4;
  const int sw8 = (fr & 7) * 8;  // read-side swizzle

  const int srow = tid >> 3;
  const int scol = 8 * ((tid & 7) ^ (srow & 7));
  const int ldst = wave * 512;

  f32x4 acc[4][4] = {};

  for (int kt = 0; kt < K; kt += 64) {
    __syncthreads();
#pragma unroll
    for (int s = 0; s < 4; ++s) {
      const int row = s * 32 + srow;
      async_load16(A + (size_t)(bm + row) * K + kt + scol,
                   (void*)(As + s * 2048 + ldst));
      async_load16(B + (size_t)(bn + row) * K + kt + scol,
                   (void*)(Bs + s * 2048 + ldst));
    }
    __syncthreads();

#pragma unroll
    for (int ks = 0; ks < 2; ++ks) {
      bf16x8 af[4], bfr[4];
      const int kq = (ks * 32 + g * 8) ^ sw8;
#pragma unroll
      for (int i = 0; i < 4; ++i)
        af[i] = *(const bf16x8*)&As[(wm + i * 16 + fr) * 64 + kq];
#pragma unroll
      for (int j = 0; j < 4; ++j)
        bfr[j] = *(const bf16x8*)&Bs[(wn + j * 16 + fr) * 64 + kq];
#pragma unroll
      for (int i = 0; i < 4; ++i)
#pragma unroll
        for (int j = 0; j < 4; ++j)
          acc[i][j] = __builtin_amdgcn_mfma_f32_16x16x32_bf16(af[i], bfr[j],
                                                              acc[i][j], 0, 0, 0);
    }
  }

  const int r0 = (lane >> 4) * 4, cc = lane & 15;
  const bool oddl = cc & 1;
#pragma unroll
  for (int i = 0; i < 4; ++i) {
    const int row0 = bm + wm + i * 16 + r0;
    const int b = row0 >> 11, s0 = row0 & 2047;
#pragma unroll
    for (int j = 0; j < 4; ++j) {
      const int col = bn + wn + j * 16 + cc;  // whole wave same region per j
      if (col < 2048) {
        // RoPE: pair partner is lane^1 (col 2k <-> 2k+1)
        const int hcol = col & 1023;
        const int h = hcol >> 6, d = hcol & 63;
        const int ip = d >> 1;
        const bool isK = col >= 1024;
        bf16* dst = (isK ? Kh : Qh) + ((size_t)(b * 16 + h) * 2048) * 64;
#pragma unroll
        for (int r = 0; r < 4; ++r) {
          float own = acc[i][j][r];
          float oth = __shfl_xor(own, 1, 64);
          const float2 t = rope[((s0 + r) << 5) + ip];
          float res = oddl ? (oth * t.y + own * t.x) : (own * t.x - oth * t.y);
          const int dd = isK ? (d ^ (((s0 + r) & 7) << 3)) : d;
          dst[(size_t)(s0 + r) * 64 + dd] = (bf16)res;
        }
      } else {
        const int v = col - 2048, h = v >> 6, d = v & 63;
        bf16x4 o;
#pragma unroll
        for (int r = 0; r < 4; ++r) o[r] = (bf16)acc[i][j][r];
        const int s2 = (s0 & ~63) | ((s0 ^ ((d & 7) << 3)) & 63);
        *(bf16x4*)&Vt[(((size_t)b * 16 + h) * 64 + d) * 2048 + s2] = o;
      }
    }
  }
}

// ---------------------------------------------------------------------------
// Kernel 2b (out-proj): C(MxN) = A(MxK) @ B(NxK)^T, fp32 out.
// BK=64 + both-sides-swizzle structure (r19, unchanged).
// ---------------------------------------------------------------------------
template <typename OutT, int BM, int BN>
__global__ __launch_bounds__(256) void gemm_bt(
    const bf16* __restrict__ A, const bf16* __restrict__ B,
    OutT* __restrict__ C, int M, int N, int K) {
  constexpr int FM = BM / 32, FN = BN / 32;
  constexpr int SA = BM / 32, SB = BN / 32;
  __shared__ __align__(16) bf16 As[BM * 64];
  __shared__ __align__(16) bf16 Bs[BN * 64];
  const int tid = threadIdx.x;
  const int wave = tid >> 6, lane = tid & 63;
  const int bm = blockIdx.y * BM, bn = blockIdx.x * BN;
  const int wm = (wave >> 1) * (BM / 2), wn = (wave & 1) * (BN / 2);
  const int fr = lane & 15, g = lane >> 4;
  const int sw8 = (fr & 7) * 8;
  const int srow = tid >> 3;
  const int scol = 8 * ((tid & 7) ^ (srow & 7));
  const int ldst = wave * 512;

  f32x4 acc[FM][FN] = {};

  for (int kt = 0; kt < K; kt += 64) {
    __syncthreads();
#pragma unroll
    for (int s = 0; s < SA; ++s)
      async_load16(A + (size_t)(bm + s * 32 + srow) * K + kt + scol,
                   (void*)(As + s * 2048 + ldst));
#pragma unroll
    for (int s = 0; s < SB; ++s)
      async_load16(B + (size_t)(bn + s * 32 + srow) * K + kt + scol,
                   (void*)(Bs + s * 2048 + ldst));
    __syncthreads();

#pragma unroll
    for (int ks = 0; ks < 2; ++ks) {
      const int kq = (ks * 32 + g * 8) ^ sw8;
      bf16x8 af[FM], bfr[FN];
#pragma unroll
      for (int i = 0; i < FM; ++i)
        af[i] = *(const bf16x8*)&As[(wm + i * 16 + fr) * 64 + kq];
#pragma unroll
      for (int j = 0; j < FN; ++j)
        bfr[j] = *(const bf16x8*)&Bs[(wn + j * 16 + fr) * 64 + kq];
#pragma unroll
      for (int i = 0; i < FM; ++i)
#pragma unroll
        for (int j = 0; j < FN; ++j)
          acc[i][j] = __builtin_amdgcn_mfma_f32_16x16x32_bf16(af[i], bfr[j],
                                                              acc[i][j], 0, 0, 0);
    }
  }

  const int r0 = (lane >> 4) * 4, cc = lane & 15;
#pragma unroll
  for (int i = 0; i < FM; ++i)
#pragma unroll
    for (int j = 0; j < FN; ++j)
#pragma unroll
      for (int r = 0; r < 4; ++r)
        C[(size_t)(bm + wm + i * 16 + r0 + r) * N + (bn + wn + j * 16 + cc)] =
            (OutT)acc[i][j][r];
}

// ---------------------------------------------------------------------------
// Kernel 3: causal attention — ROUND 25: REVERT to the r19 configuration
// (round-5/6 source verbatim), the twice-measured best (44.96/44.8us,
// FETCH 12.3MB, zero spill).
// Why: r24 settled the TLP-vs-ILP question — serial body at 3 waves/SIMD
// (25% occupancy) = 54.2us vs r19's pipelined body at 2 waves/SIMD (11.5%)
// = 44.8us. In-wave ILP is the ~9us lever; occupancy is worth ~nothing.
// r22's attempt to get both spilled (needs >170 regs). Plateau for the
// 16x16-fragment family is ~45us; past it requires the 8-warp 32x32
// co-designed port (T2+T3+T4+T5+T10 dependency graph).
//   * Mapping: xcd=f&7, u=(f>>3)&31, v=f>>8; bh=xcd+8*(u&3) (4 bh/XCD,
//     2MB, L2-fits); j = v ? u>>2 : 15-(u>>2) (complementary pairing).
//   * T4 counted vmcnt: iter i consumes K(i) (staged 2 iters ago) and
//     V(i-1), stages tile i+2; s_waitcnt vmcnt(4) + raw s_barrier; no
//     vmcnt(0) until the last 2 iters. K 3 slots, V 4 slots, LDS 56KB.
//   * Pipe order: QK(i) + PV(i-1) MFMA adjacent (setprio), exp(i) after.
// ---------------------------------------------------------------------------
__global__ __launch_bounds__(256, 2) void attn(const bf16* __restrict__ Qh,
                                               const bf16* __restrict__ Kh,
                                               const bf16* __restrict__ Vt,
                                               bf16* __restrict__ Oh) {
  __shared__ __align__(16) bf16 Ks[3][64 * 64];
  __shared__ __align__(16) bf16 Vs[4][64 * 64];
  const int f = blockIdx.x;
  const int xcd = f & 7, u = (f >> 3) & 31, v = f >> 8;
  const int bh = xcd + 8 * (u & 3);
  const int j = v ? (u >> 2) : 15 - (u >> 2);
  const int tid = threadIdx.x, w = tid >> 6, lane = tid & 63;
  const int nlo = lane & 15, g = lane >> 4;
  const int q0 = j * 128, qw0 = q0 + w * 32;  // this wave's 32 q-rows
  const bf16* __restrict__ Qp = Qh + (size_t)bh * 131072;
  const bf16* __restrict__ Kp = Kh + (size_t)bh * 131072;
  const bf16* __restrict__ Vp = Vt + (size_t)bh * 131072;
  const int n = 2 * (j + 1);            // k-tiles for this block
  const int nw = 2 * j + (w >> 1) + 1;  // k-tiles this wave computes

  // Q fragments (B-operand: n=q=nlo, k=d), linear Qh
  bf16x8 aq[2][2];
#pragma unroll
  for (int qb = 0; qb < 2; ++qb)
#pragma unroll
    for (int ks = 0; ks < 2; ++ks)
      aq[qb][ks] =
          *(const bf16x8*)&Qp[(size_t)(qw0 + qb * 16 + nlo) * 64 + ks * 32 + g * 8];

  f32x4 oacc[2][4] = {};  // [qb][d-block], O^T C-layout (m=d, n=q)
  float lsum[2] = {0.f, 0.f};
  const int sw = (nlo & 7) << 3;  // inverse XOR for swizzled LDS reads

  // Staging: wave w stages rows w*16..w*16+15 of each 64x64 tile.
  const int srow = w * 16 + (lane >> 3);
  const int soff = (lane & 7) * 8;

  auto stage = [&](int i) {
    const int kbase = i * 64, sk = i % 3, sv = i & 3;
    async_load16(Kp + (size_t)(kbase + srow) * 64 + soff,
                 (void*)(Ks[sk] + w * 1024));
    async_load16(Kp + (size_t)(kbase + srow + 8) * 64 + soff,
                 (void*)(Ks[sk] + w * 1024 + 512));
    async_load16(Vp + (size_t)srow * 2048 + kbase + soff,
                 (void*)(Vs[sv] + w * 1024));
    async_load16(Vp + (size_t)(srow + 8) * 2048 + kbase + soff,
                 (void*)(Vs[sv] + w * 1024 + 512));
  };

  bf16x8 pk[4][2];
  auto rdK = [&](int slot) {
    const bf16* __restrict__ Kw = Ks[slot];
#pragma unroll
    for (int ni = 0; ni < 4; ++ni)
#pragma unroll
      for (int ks = 0; ks < 2; ++ks)
        pk[ni][ks] =
            *(const bf16x8*)&Kw[(ni * 16 + nlo) * 64 + ((ks * 32 + g * 8) ^ sw)];
  };

  bf16x4 av[4][4];
  auto rdV = [&](int slot) {
    const bf16* __restrict__ Vw = Vs[slot];
#pragma unroll
    for (int ni = 0; ni < 4; ++ni)
#pragma unroll
      for (int mi = 0; mi < 4; ++mi)
        av[ni][mi] =
            *(const bf16x4*)&Vw[(mi * 16 + nlo) * 64 + ((ni * 16 + g * 4) ^ sw)];
  };

  f32x4 st[2][4];
  auto qk = [&]() {
#pragma unroll
    for (int qb = 0; qb < 2; ++qb) {
#pragma unroll
      for (int ni = 0; ni < 4; ++ni) st[qb][ni] = f32x4{0.f, 0.f, 0.f, 0.f};
#pragma unroll
      for (int ks = 0; ks < 2; ++ks)
#pragma unroll
        for (int ni = 0; ni < 4; ++ni)
          st[qb][ni] = __builtin_amdgcn_mfma_f32_16x16x32_bf16(
              pk[ni][ks], aq[qb][ks], st[qb][ni], 0, 0, 0);
    }
  };

  bf16x4 p[2][4];
  auto expv = [&](int i) {
    const int kbase = i * 64;
    const bool dg = (i == nw - 1);  // diagonal tile (wave-uniform)
#pragma unroll
    for (int qb = 0; qb < 2; ++qb) {
      const int qg = qw0 + qb * 16 + nlo;
      if (!dg) {
#pragma unroll
        for (int ni = 0; ni < 4; ++ni)
#pragma unroll
          for (int r = 0; r < 4; ++r) {
            float e = __builtin_amdgcn_exp2f(st[qb][ni][r]);
            lsum[qb] += e;
            p[qb][ni][r] = (bf16)e;
          }
      } else {
#pragma unroll
        for (int ni = 0; ni < 4; ++ni) {
          const int kg0 = kbase + ni * 16 + g * 4;
#pragma unroll
          for (int r = 0; r < 4; ++r) {
            float e = __builtin_amdgcn_exp2f(st[qb][ni][r]);
            e = (kg0 + r <= qg) ? e : 0.0f;
            lsum[qb] += e;
            p[qb][ni][r] = (bf16)e;
          }
        }
      }
    }
  };

  auto pv = [&]() {
#pragma unroll
    for (int ni = 0; ni < 4; ++ni)
#pragma unroll
      for (int mi = 0; mi < 4; ++mi)
#pragma unroll
        for (int qb = 0; qb < 2; ++qb)
          oacc[qb][mi] = mfma16(av[ni][mi], p[qb][ni], oacc[qb][mi]);
  };

  // ---- prologue: stage tiles 0,1; counted wait (stage(1) stays in flight)
  stage(0);
  stage(1);
  asm volatile("s_waitcnt vmcnt(4)" ::: "memory");
  __builtin_amdgcn_s_barrier();

  // ---- main loop: iter i = QK(i) + PV(i-1) + exp(i); stage(i+2) ----
  for (int i = 0; i < n; ++i) {
    if (i + 2 < n) stage(i + 2);
    const bool doQK = (i < nw);      // wave-uniform
    const bool doPV = (i > 0);       // P(i-1) valid for all waves (nw>=n-1)
    if (doQK) rdK(i % 3);
    if (doPV) rdV((i - 1) & 3);
    __builtin_amdgcn_s_setprio(1);
    if (doQK) qk();
    if (doPV) pv();
    __builtin_amdgcn_s_setprio(0);
    if (doQK) expv(i);
    if (i + 2 < n)
      asm volatile("s_waitcnt vmcnt(4)" ::: "memory");
    else
      asm volatile("s_waitcnt vmcnt(0)" ::: "memory");
    __builtin_amdgcn_s_barrier();
  }

  // ---- epilogue: waves owning tile n-1 finish PV(n-1) ----
  if (nw == n) {
    rdV((n - 1) & 3);
    pv();
  }

  // finish l: reduce over the 4 g-groups (columns are per-nlo)
#pragma unroll
  for (int qb = 0; qb < 2; ++qb) {
    lsum[qb] += __shfl_xor(lsum[qb], 16, 64);
    lsum[qb] += __shfl_xor(lsum[qb], 32, 64);
  }

  // each wave writes its own rows; no combine needed
  const int bb = bh >> 4, hd = bh & 15;
#pragma unroll
  for (int qb = 0; qb < 2; ++qb) {
    const float inv = 1.0f / lsum[qb];
    const int q = qw0 + qb * 16 + nlo;
#pragma unroll
    for (int mi = 0; mi < 4; ++mi) {
      bf16x4 o;
#pragma unroll
      for (int r = 0; r < 4; ++r) o[r] = (bf16)(oacc[qb][mi][r] * inv);
      *(bf16x4*)&Oh[((size_t)bb * 2048 + q) * 1024 + hd * 64 + mi * 16 + g * 4] = o;
    }
  }
}

// ---------------------------------------------------------------------------
extern "C" void kernel_launch(void* const* d_in, const int* in_sizes, int n_in,
                              void* d_out, int out_size, void* d_ws, size_t ws_size,
                              hipStream_t stream) {
  (void)in_sizes; (void)n_in; (void)out_size; (void)ws_size;
  const float* x = (const float*)d_in[0];
  const float* Wq = (const float*)d_in[1];
  const float* Wk = (const float*)d_in[2];
  const float* Wv = (const float*)d_in[3];
  const float* Wo = (const float*)d_in[4];
  float* out = (float*)d_out;
  char* ws = (char*)d_ws;

  bf16* Xh    = (bf16*)(ws);                 // 4096x1024          8 MB
  bf16* Wqkv  = (bf16*)(ws + 8388608);       // 3072x1024          6 MB
  bf16* Woh   = (bf16*)(ws + 14680064);      // 1024x1024          2 MB
  bf16* Qh    = (bf16*)(ws + 16777216);      // [32][2048][64]     8 MB
  bf16* Kh    = (bf16*)(ws + 25165824);      // [32][2048][64]     8 MB (d-swizzled)
  bf16* Vt    = (bf16*)(ws + 33554432);      // [32][64][2048]     8 MB (col-swizzled)
  bf16* Oh    = (bf16*)(ws + 41943040);      // 4096x1024          8 MB
  float2* rope = (float2*)(ws + 50331648);   // [2048][32] cos/sin 512 KB

  cast_all<<<8256, 256, 0, stream>>>(x, Wq, Wk, Wv, Wo, Xh, Wqkv, Woh, rope);
  gemm_qkv<<<dim3(24, 32), 256, 0, stream>>>(Xh, Wqkv, rope, Qh, Kh, Vt, 1024);
  attn<<<512, 256, 0, stream>>>(Qh, Kh, Vt, Oh);
  gemm_bt<float, 128, 128><<<dim3(8, 32), 256, 0, stream>>>(Oh, Woh, out, 4096, 1024, 1024);
}